// Round 1
// baseline (69.686 us; speedup 1.0000x reference)
//
#include <hip/hip_runtime.h>

#define EMB 128
#define BM 128
#define K2 256          // combined K = 2*EMB  ([h|r] @ [De;Dr])
#define THREADS 512     // 8 waves

typedef __attribute__((ext_vector_type(8))) short bf16x8;   // 8 bf16 (4 VGPRs)
typedef __attribute__((ext_vector_type(4))) float f32x4;

__device__ __forceinline__ unsigned short f2bf(float f) {
    unsigned u = __builtin_bit_cast(unsigned, f);
    u += 0x7fffu + ((u >> 16) & 1u);           // round-to-nearest-even
    return (unsigned short)(u >> 16);
}

union SMem {
    struct { unsigned short A[BM][K2]; unsigned short B[EMB][K2]; } mm; // 64KB + 64KB, XOR-swizzled
    struct { float F[BM][EMB + 4]; } ep;                                // 67.6KB, +4 pad breaks conflicts
};

__global__ __launch_bounds__(THREADS, 1)
void projE_kernel(const int* __restrict__ triple,
                  const float* __restrict__ ent,
                  const float* __restrict__ relt,
                  const float* __restrict__ De,
                  const float* __restrict__ Dr,
                  const float* __restrict__ bc,
                  float* __restrict__ out)
{
    __shared__ SMem sm;
    const int tid  = threadIdx.x;
    const int lane = tid & 63;
    const int w    = tid >> 6;              // wave 0..7
    const int bm0  = blockIdx.x * BM;

    // ---------------- stage A: sA[row][k] = bf16([h_row | r_row]), swizzled ----------------
    {
        const int seg   = lane & 31;        // float4 segment 0..31 (covers 128 floats)
        const int rhalf = lane >> 5;        // 2 rows per wave-round
        for (int rr = 0; rr < 16; rr += 2) {
            const int row  = w * 16 + rr + rhalf;
            const long g   = bm0 + row;
            const int hidx = triple[g * 3 + 0];
            const int ridx = triple[g * 3 + 1];
            const float4 hv = *reinterpret_cast<const float4*>(ent  + (long)hidx * EMB + seg * 4);
            const float4 rv = *reinterpret_cast<const float4*>(relt + (long)ridx * EMB + seg * 4);
            const int sw = (row & 7) << 3;                  // element-index XOR swizzle (16B granules)
            const int ka = (seg * 4) ^ sw;                  // h -> k in [0,128)
            const int kb = (128 + seg * 4) ^ sw;            // r -> k in [128,256)
            ushort4 hp = { f2bf(hv.x), f2bf(hv.y), f2bf(hv.z), f2bf(hv.w) };
            ushort4 rp = { f2bf(rv.x), f2bf(rv.y), f2bf(rv.z), f2bf(rv.w) };
            *reinterpret_cast<ushort4*>(&sm.mm.A[row][ka]) = hp;
            *reinterpret_cast<ushort4*>(&sm.mm.A[row][kb]) = rp;
        }
    }

    // ---------------- stage B^T: sB[n][k] = bf16(k<128 ? De[k][n] : Dr[k-128][n]), swizzled ----------------
    for (int s = 0; s < 8; ++s) {
        const int t2 = s * THREADS + tid;       // 4096 tasks of 8 elements
        const int n  = t2 & 127;
        const int k0 = (t2 >> 7) * 8;
        const float* src = (k0 < 128) ? (De + (long)k0 * EMB + n)
                                      : (Dr + (long)(k0 - 128) * EMB + n);
        unsigned short p[8];
        #pragma unroll
        for (int m = 0; m < 8; ++m) p[m] = f2bf(src[(long)m * EMB]);
        const int ke = k0 ^ ((n & 7) << 3);
        *reinterpret_cast<ushort4*>(&sm.mm.B[n][ke])     = *reinterpret_cast<ushort4*>(&p[0]);
        *reinterpret_cast<ushort4*>(&sm.mm.B[n][ke + 4]) = *reinterpret_cast<ushort4*>(&p[4]);
    }

    __syncthreads();

    // ---------------- MFMA: F(128x128) = A(128x256) @ B(256x128) ----------------
    const int wm  = w >> 1;                 // row tile: wm*32
    const int wn  = w & 1;                  // col tile: wn*64
    const int l15 = lane & 15;
    const int l4  = lane >> 4;              // 0..3

    f32x4 acc[2][4];
    #pragma unroll
    for (int mi = 0; mi < 2; ++mi)
        #pragma unroll
        for (int ni = 0; ni < 4; ++ni)
            acc[mi][ni] = (f32x4){0.f, 0.f, 0.f, 0.f};

    #pragma unroll
    for (int kk = 0; kk < 8; ++kk) {
        const int k0 = kk * 32 + 8 * l4;    // this lane's 8-element k slice
        bf16x8 a[2], b[4];
        #pragma unroll
        for (int mi = 0; mi < 2; ++mi) {
            const int row = wm * 32 + mi * 16 + l15;
            a[mi] = *reinterpret_cast<const bf16x8*>(&sm.mm.A[row][k0 ^ ((row & 7) << 3)]);
        }
        #pragma unroll
        for (int ni = 0; ni < 4; ++ni) {
            const int n = wn * 64 + ni * 16 + l15;
            b[ni] = *reinterpret_cast<const bf16x8*>(&sm.mm.B[n][k0 ^ ((n & 7) << 3)]);
        }
        #pragma unroll
        for (int mi = 0; mi < 2; ++mi)
            #pragma unroll
            for (int ni = 0; ni < 4; ++ni)
                acc[mi][ni] = __builtin_amdgcn_mfma_f32_16x16x32_bf16(a[mi], b[ni], acc[mi][ni], 0, 0, 0);
    }

    __syncthreads();   // done reading sA/sB; union region becomes F

    // ---------------- epilogue 1: F = tanh(acc + b_c) ----------------
    #pragma unroll
    for (int mi = 0; mi < 2; ++mi) {
        #pragma unroll
        for (int ni = 0; ni < 4; ++ni) {
            const int col = wn * 64 + ni * 16 + l15;
            #pragma unroll
            for (int r = 0; r < 4; ++r) {
                const int row = wm * 32 + mi * 16 + 4 * l4 + r;
                const float x = acc[mi][ni][r] + bc[(long)(bm0 + row) * EMB + col];
                const float e = __expf(2.f * x);
                sm.ep.F[row][col] = 1.f - 2.f / (e + 1.f);   // tanh(x)
            }
        }
    }
    __syncthreads();

    // ---------------- epilogue 2: out = sigmoid(sum_j F[row][j] * t[row][j]) ----------------
    const int tseg  = lane & 31;
    const int thalf = lane >> 5;
    float partial[8];
    #pragma unroll
    for (int s = 0; s < 8; ++s) {
        const int row  = w * 16 + 2 * s + thalf;
        const int tidx = triple[(long)(bm0 + row) * 3 + 2];
        const float4 tv = *reinterpret_cast<const float4*>(ent + (long)tidx * EMB + tseg * 4);
        const float4 fv = *reinterpret_cast<const float4*>(&sm.ep.F[row][tseg * 4]);
        partial[s] = tv.x * fv.x + tv.y * fv.y + tv.z * fv.z + tv.w * fv.w;
    }
    #pragma unroll
    for (int s = 0; s < 8; ++s) {
        float v = partial[s];
        v += __shfl_xor(v, 16);
        v += __shfl_xor(v, 8);
        v += __shfl_xor(v, 4);
        v += __shfl_xor(v, 2);
        v += __shfl_xor(v, 1);
        if ((lane & 31) == 0) {
            const int row = w * 16 + 2 * s + thalf;
            out[bm0 + row] = 1.f / (1.f + __expf(-v));
        }
    }
}

extern "C" void kernel_launch(void* const* d_in, const int* in_sizes, int n_in,
                              void* d_out, int out_size, void* d_ws, size_t ws_size,
                              hipStream_t stream) {
    const int*   triple = (const int*)  d_in[0];
    const float* ent    = (const float*)d_in[1];
    const float* relt   = (const float*)d_in[2];
    const float* De     = (const float*)d_in[3];
    const float* Dr     = (const float*)d_in[4];
    const float* bc     = (const float*)d_in[5];
    float* out = (float*)d_out;

    const int batch = in_sizes[0] / 3;          // 131072
    dim3 grid(batch / BM);                      // 1024 blocks
    projE_kernel<<<grid, THREADS, 0, stream>>>(triple, ent, relt, De, Dr, bc, out);
}

// Round 2
// 45.331 us; speedup vs baseline: 1.5373x; 1.5373x over previous
//
#include <hip/hip_runtime.h>

#define EMB 128
#define BM 128
#define THREADS 512

typedef __attribute__((ext_vector_type(8))) short bf16x8;   // 8 bf16 (4 VGPRs)
typedef __attribute__((ext_vector_type(4))) float f32x4;
typedef unsigned short u16;

__device__ __forceinline__ u16 f2bf(float f) {
    unsigned u = __builtin_bit_cast(unsigned, f);
    u += 0x7fffu + ((u >> 16) & 1u);           // round-to-nearest-even
    return (u16)(u >> 16);
}

// ---- pre-kernel 1: Rp[j][n] = sum_k rel[j][k] * Dr[k][n]  (f32, 1000x128) ----
__global__ void relproj_kernel(const float* __restrict__ rel,
                               const float* __restrict__ Dr,
                               float* __restrict__ Rp, int nrel) {
    const int n  = threadIdx.x;          // 0..127
    const int j0 = blockIdx.x * 4;
    if (j0 >= nrel) return;
    float a0 = 0.f, a1 = 0.f, a2 = 0.f, a3 = 0.f;
    for (int k = 0; k < EMB; ++k) {
        const float dr = Dr[k * EMB + n];              // coalesced row read
        a0 = fmaf(rel[(j0 + 0) * EMB + k], dr, a0);    // uniform (s_load) broadcasts
        a1 = fmaf(rel[(j0 + 1) * EMB + k], dr, a1);
        a2 = fmaf(rel[(j0 + 2) * EMB + k], dr, a2);
        a3 = fmaf(rel[(j0 + 3) * EMB + k], dr, a3);
    }
    Rp[(j0 + 0) * EMB + n] = a0;
    Rp[(j0 + 1) * EMB + n] = a1;
    Rp[(j0 + 2) * EMB + n] = a2;
    Rp[(j0 + 3) * EMB + n] = a3;
}

// ---- pre-kernel 2: frag-major bf16 image of De (B-operand for 16x16x32) ----
// Bimg[((kk*8+ni)*64 + lane)*8 + e] = bf16( De[kk*32 + (lane>>4)*8 + e][ni*16 + (lane&15)] )
__global__ void bimg_kernel(const float* __restrict__ De, u16* __restrict__ Bimg) {
    const int idx  = blockIdx.x * 256 + threadIdx.x;   // 0..16383
    const int e    = idx & 7;
    const int lane = (idx >> 3) & 63;
    const int frag = idx >> 9;                         // 0..31
    const int ni = frag & 7, kk = frag >> 3;
    const int k = kk * 32 + (lane >> 4) * 8 + e;
    const int n = ni * 16 + (lane & 15);
    Bimg[idx] = f2bf(De[k * EMB + n]);
}

// ---- main kernel ----
__global__ __launch_bounds__(THREADS, 4)
void projE_main(const int* __restrict__ triple,
                const float* __restrict__ ent,
                const float* __restrict__ bc,
                const float* __restrict__ Rp,
                const u16* __restrict__ Bimg,
                float* __restrict__ out)
{
    __shared__ u16 As[BM][EMB];     // 32KB, XOR-swizzled rows
    __shared__ u16 Bs[16384];       // 32KB, frag-major (conflict-free reads)

    const int tid  = threadIdx.x;
    const int lane = tid & 63;
    const int w    = tid >> 6;      // wave 0..7, owns rows w*16..w*16+15
    const int l15  = lane & 15;
    const int l4   = lane >> 4;
    const int bm0  = blockIdx.x * BM;

    // ---- stage B: 32KB linear copy, global -> LDS direct (16B per lane) ----
    {
        const __attribute__((address_space(1))) char* gB =
            (const __attribute__((address_space(1))) char*)Bimg;
        __attribute__((address_space(3))) char* lB =
            (__attribute__((address_space(3))) char*)Bs;
        #pragma unroll
        for (int i = 0; i < 4; ++i) {
            const int off = (i * THREADS + tid) * 16;   // wave-uniform base + lane*16
            __builtin_amdgcn_global_load_lds(
                (const __attribute__((address_space(1))) void*)(gB + off),
                (__attribute__((address_space(3))) void*)(lB + off), 16, 0, 0);
        }
    }

    // ---- stage A: this wave's 16 h-rows -> bf16 LDS, swizzled ----
    {
        const int seg   = lane & 31;        // float4 segment within a 512B row
        const int rhalf = lane >> 5;
        #pragma unroll
        for (int it = 0; it < 8; ++it) {
            const int row  = w * 16 + it * 2 + rhalf;
            const int g    = bm0 + row;
            const int hidx = triple[g * 3];
            const float4 hv = *reinterpret_cast<const float4*>(ent + (size_t)hidx * EMB + seg * 4);
            ushort4 hp = { f2bf(hv.x), f2bf(hv.y), f2bf(hv.z), f2bf(hv.w) };
            *reinterpret_cast<ushort4*>(&As[row][(seg * 4) ^ ((row & 7) << 3)]) = hp;
        }
    }

    __syncthreads();   // the only barrier (covers B-copy completion + cross-lane A)

    // ---- MFMA: F[w*16..+15][0..127] = A @ De, K=128 ----
    f32x4 acc[8];
    #pragma unroll
    for (int ni = 0; ni < 8; ++ni) acc[ni] = (f32x4){0.f, 0.f, 0.f, 0.f};

    const int arow = w * 16 + l15;
    const int asw  = (arow & 7) << 3;
    #pragma unroll
    for (int kk = 0; kk < 4; ++kk) {
        const bf16x8 a = *reinterpret_cast<const bf16x8*>(&As[arow][(kk * 32 + 8 * l4) ^ asw]);
        #pragma unroll
        for (int ni = 0; ni < 8; ++ni) {
            const bf16x8 b = *reinterpret_cast<const bf16x8*>(&Bs[(kk * 8 + ni) * 512 + lane * 8]);
            acc[ni] = __builtin_amdgcn_mfma_f32_16x16x32_bf16(a, b, acc[ni], 0, 0, 0);
        }
    }

    // ---- epilogue (no barrier): f = tanh(acc + Rp[ridx] + bc); out = sigmoid(f . t) ----
    #pragma unroll
    for (int r = 0; r < 4; ++r) {
        const int row  = w * 16 + 4 * l4 + r;      // C-frag: row = 4*l4 + reg
        const int g    = bm0 + row;
        const int ridx = triple[g * 3 + 1];
        const int tidx = triple[g * 3 + 2];
        const float* rp = Rp  + (size_t)ridx * EMB;
        const float* bp = bc  + (size_t)g    * EMB;
        const float* tp = ent + (size_t)tidx * EMB;
        float dot = 0.f;
        #pragma unroll
        for (int ni = 0; ni < 8; ++ni) {
            const int col = ni * 16 + l15;         // C-frag: col = l15
            const float x  = acc[ni][r] + rp[col] + bp[col];
            const float e2 = __expf(2.f * x);
            const float fv = 1.f - __fdividef(2.f, e2 + 1.f);   // tanh(x), inf-safe
            dot = fmaf(fv, tp[col], dot);
        }
        dot += __shfl_xor(dot, 1);
        dot += __shfl_xor(dot, 2);
        dot += __shfl_xor(dot, 4);
        dot += __shfl_xor(dot, 8);
        if (l15 == 0) out[g] = __fdividef(1.f, 1.f + __expf(-dot));
    }
}

extern "C" void kernel_launch(void* const* d_in, const int* in_sizes, int n_in,
                              void* d_out, int out_size, void* d_ws, size_t ws_size,
                              hipStream_t stream) {
    const int*   triple = (const int*)  d_in[0];
    const float* ent    = (const float*)d_in[1];
    const float* rel    = (const float*)d_in[2];
    const float* De     = (const float*)d_in[3];
    const float* Dr     = (const float*)d_in[4];
    const float* bc     = (const float*)d_in[5];
    float* out = (float*)d_out;

    const int batch = in_sizes[0] / 3;          // 131072
    const int nrel  = in_sizes[2] / EMB;        // 1000

    float* Rp = (float*)d_ws;                           // 512000 B
    u16* Bimg = (u16*)((char*)d_ws + 524288);           // 32 KB

    relproj_kernel<<<dim3((nrel + 3) / 4), dim3(EMB), 0, stream>>>(rel, Dr, Rp, nrel);
    bimg_kernel<<<dim3(64), dim3(256), 0, stream>>>(De, Bimg);
    projE_main<<<dim3(batch / BM), dim3(THREADS), 0, stream>>>(triple, ent, bc, Rp, Bimg, out);
}